// Round 2
// baseline (635.538 us; speedup 1.0000x reference)
//
#include <hip/hip_runtime.h>
#include <math.h>

#define NPB 4096
#define BB 2
#define NN (NPB*BB)          // 8192
#define DIM 64
#define KK 5
#define NKR (NPB*KK)         // 20480
#define ET (BB*NKR)          // 40960 edges (= b*n*K)
#define RSPLIT 4
#define TILES_PER_SPLIT ((NPB/RSPLIT)/64)   // 16

__device__ __forceinline__ float clip_exp(const float* tptr) {
    return expf(fminf(fmaxf(tptr[0], -5.0f), 5.0f));
}

// order-preserving float <-> uint map for atomicMax-based segment max
__device__ __forceinline__ unsigned enc_f(float f) {
    unsigned u = __float_as_uint(f);
    return (u & 0x80000000u) ? ~u : (u | 0x80000000u);
}
__device__ __forceinline__ float dec_f(unsigned e) {
    unsigned u = (e & 0x80000000u) ? (e ^ 0x80000000u) : ~e;
    return __uint_as_float(u);
}

// insert (dd,ii) into ascending top-5; strict-less compare (valid when ii is
// scanned in increasing order: equal-d keeps the earlier/lower index)
__device__ __forceinline__ void ins5(float& d0, float& d1, float& d2, float& d3, float& d4,
                                     int& i0, int& i1, int& i2, int& i3, int& i4,
                                     float dd, int ii) {
    if (dd < d4) {
        bool c0 = dd < d0, c1 = dd < d1, c2 = dd < d2, c3 = dd < d3;
        d4 = c3 ? d3 : dd;             i4 = c3 ? i3 : ii;
        d3 = c2 ? d2 : (c3 ? dd : d3); i3 = c2 ? i2 : (c3 ? ii : i3);
        d2 = c1 ? d1 : (c2 ? dd : d2); i2 = c1 ? i1 : (c2 ? ii : i2);
        d1 = c0 ? d0 : (c1 ? dd : d1); i1 = c0 ? i0 : (c1 ? ii : i1);
        d0 = c0 ? dd : d0;             i0 = c0 ? ii : i0;
    }
}

// lexicographic (d, idx) insert — for merging lists in arbitrary order
__device__ __forceinline__ void ins5lex(float& d0, float& d1, float& d2, float& d3, float& d4,
                                        int& i0, int& i1, int& i2, int& i3, int& i4,
                                        float dd, int ii) {
    bool c4 = (dd < d4) || (dd == d4 && ii < i4);
    if (c4) {
        bool c0 = (dd < d0) || (dd == d0 && ii < i0);
        bool c1 = (dd < d1) || (dd == d1 && ii < i1);
        bool c2 = (dd < d2) || (dd == d2 && ii < i2);
        bool c3 = (dd < d3) || (dd == d3 && ii < i3);
        d4 = c3 ? d3 : dd;             i4 = c3 ? i3 : ii;
        d3 = c2 ? d2 : (c3 ? dd : d3); i3 = c2 ? i2 : (c3 ? ii : i3);
        d2 = c1 ? d1 : (c2 ? dd : d2); i2 = c1 ? i1 : (c2 ? ii : i2);
        d1 = c0 ? d0 : (c1 ? dd : d1); i1 = c0 ? i0 : (c1 ? ii : i1);
        d0 = c0 ? dd : d0;             i0 = c0 ? ii : i0;
    }
}

// ---------------- pre_fc: Y = leaky_relu(X[8192,32] @ W[32,64] + b, 0.1)
__global__ __launch_bounds__(256) void k_prefc(const float* __restrict__ X,
        const float* __restrict__ W, const float* __restrict__ bias,
        float* __restrict__ Y) {
    int row = blockIdx.x * 4 + (threadIdx.x >> 6);
    int c = threadIdx.x & 63;
    const float* xr = X + (size_t)row * 32;
    float acc = bias[c];
#pragma unroll
    for (int d = 0; d < 32; ++d) acc = fmaf(xr[d], W[d * 64 + c], acc);
    Y[(size_t)row * 64 + c] = acc > 0.f ? acc : 0.1f * acc;
}

// ---------------- embed: Y = X1@W[0:64] (+ X2@W[64:128]) + b ; also sq-norms of rows of Y
__global__ __launch_bounds__(256) void k_embed(const float* __restrict__ X1,
        const float* __restrict__ X2, const float* __restrict__ W,
        const float* __restrict__ bias, float* __restrict__ Y,
        float* __restrict__ sqout) {
    int row = blockIdx.x * 4 + (threadIdx.x >> 6);
    int c = threadIdx.x & 63;
    float acc = bias[c];
    const float* x1r = X1 + (size_t)row * DIM;
#pragma unroll 16
    for (int d = 0; d < DIM; ++d) acc = fmaf(x1r[d], W[d * DIM + c], acc);
    if (X2) {
        const float* x2r = X2 + (size_t)row * DIM;
#pragma unroll 16
        for (int d = 0; d < DIM; ++d) acc = fmaf(x2r[d], W[(DIM + d) * DIM + c], acc);
    }
    Y[(size_t)row * DIM + c] = acc;
    float s = acc * acc;
#pragma unroll
    for (int off = 32; off; off >>= 1) s += __shfl_xor(s, off, 64);
    if (c == 0) sqout[row] = s;
}

// ---------------- knn: per (col-block, batch, row-split) partial stable top-5 smallest
__global__ __launch_bounds__(256) void k_knn(const float* __restrict__ ge,
        const float* __restrict__ sq, const float* __restrict__ tptr,
        float* __restrict__ pd, int* __restrict__ pi) {
    __shared__ float smem[2 * 64 * 81];    // 41472 B, reused between phases
    float (*gej)[65] = reinterpret_cast<float(*)[65]>(smem);
    float (*gei)[65] = reinterpret_cast<float(*)[65]>(smem + 64 * 65);
    float (*cd)[81]  = reinterpret_cast<float(*)[81]>(smem);
    int   (*ci)[81]  = reinterpret_cast<int(*)[81]>(smem + 64 * 81);

    const int b_ = blockIdx.y;
    const int rs = blockIdx.z;
    const int jblk = blockIdx.x * 64;
    const float* geb = ge + (size_t)b_ * NPB * DIM;
    const float* sqb = sq + (size_t)b_ * NPB;
    const float t = clip_exp(tptr);
    const int tid = threadIdx.x;

    for (int v = tid; v < 64 * 64; v += 256)
        gej[v >> 6][v & 63] = geb[(size_t)(jblk + (v >> 6)) * DIM + (v & 63)];

    const int rg = tid >> 4, cg = tid & 15;
    float td[4][5]; int ti[4][5];
#pragma unroll
    for (int c = 0; c < 4; ++c)
#pragma unroll
        for (int m = 0; m < 5; ++m) { td[c][m] = INFINITY; ti[c][m] = 0x7FFFFFFF; }
    float sjv[4];
#pragma unroll
    for (int c = 0; c < 4; ++c) sjv[c] = sqb[jblk + cg * 4 + c];

    const int tb0 = rs * TILES_PER_SPLIT;
    for (int tb = tb0; tb < tb0 + TILES_PER_SPLIT; ++tb) {
        __syncthreads();
        for (int v = tid; v < 64 * 64; v += 256)
            gei[v >> 6][v & 63] = geb[(size_t)(tb * 64 + (v >> 6)) * DIM + (v & 63)];
        __syncthreads();
        float accd[4][4];
#pragma unroll
        for (int r = 0; r < 4; ++r)
#pragma unroll
            for (int c = 0; c < 4; ++c) accd[r][c] = 0.f;
#pragma unroll 8
        for (int d = 0; d < 64; ++d) {
            float a0 = gei[rg * 4 + 0][d], a1 = gei[rg * 4 + 1][d];
            float a2 = gei[rg * 4 + 2][d], a3 = gei[rg * 4 + 3][d];
            float b0 = gej[cg * 4 + 0][d], b1 = gej[cg * 4 + 1][d];
            float b2 = gej[cg * 4 + 2][d], b3 = gej[cg * 4 + 3][d];
            accd[0][0] = fmaf(a0, b0, accd[0][0]);
            accd[0][1] = fmaf(a0, b1, accd[0][1]);
            accd[0][2] = fmaf(a0, b2, accd[0][2]);
            accd[0][3] = fmaf(a0, b3, accd[0][3]);
            accd[1][0] = fmaf(a1, b0, accd[1][0]);
            accd[1][1] = fmaf(a1, b1, accd[1][1]);
            accd[1][2] = fmaf(a1, b2, accd[1][2]);
            accd[1][3] = fmaf(a1, b3, accd[1][3]);
            accd[2][0] = fmaf(a2, b0, accd[2][0]);
            accd[2][1] = fmaf(a2, b1, accd[2][1]);
            accd[2][2] = fmaf(a2, b2, accd[2][2]);
            accd[2][3] = fmaf(a2, b3, accd[2][3]);
            accd[3][0] = fmaf(a3, b0, accd[3][0]);
            accd[3][1] = fmaf(a3, b1, accd[3][1]);
            accd[3][2] = fmaf(a3, b2, accd[3][2]);
            accd[3][3] = fmaf(a3, b3, accd[3][3]);
        }
#pragma unroll
        for (int r = 0; r < 4; ++r) {
            int i = tb * 64 + rg * 4 + r;
            float si = sqb[i];
#pragma unroll
            for (int c = 0; c < 4; ++c) {
                float md = fmaxf(si + sjv[c] - 2.0f * accd[r][c], 0.0f) * t;
                ins5(td[c][0], td[c][1], td[c][2], td[c][3], td[c][4],
                     ti[c][0], ti[c][1], ti[c][2], ti[c][3], ti[c][4], md, i);
            }
        }
    }
    __syncthreads();
#pragma unroll
    for (int c = 0; c < 4; ++c) {
        int col = cg * 4 + c;
#pragma unroll
        for (int m = 0; m < 5; ++m) {
            cd[col][rg * 5 + m] = td[c][m];
            ci[col][rg * 5 + m] = ti[c][m];
        }
    }
    __syncthreads();
    if (tid < 64) {
        float d0 = INFINITY, d1 = INFINITY, d2 = INFINITY, d3 = INFINITY, d4 = INFINITY;
        int i0 = 0x7FFFFFFF, i1 = 0x7FFFFFFF, i2 = 0x7FFFFFFF, i3 = 0x7FFFFFFF, i4 = 0x7FFFFFFF;
        for (int v = 0; v < 80; ++v)
            ins5lex(d0, d1, d2, d3, d4, i0, i1, i2, i3, i4, cd[tid][v], ci[tid][v]);
        size_t base = ((size_t)(b_ * RSPLIT + rs) * NPB + jblk + tid) * KK;
        pd[base + 0] = d0; pd[base + 1] = d1; pd[base + 2] = d2; pd[base + 3] = d3; pd[base + 4] = d4;
        pi[base + 0] = i0; pi[base + 1] = i1; pi[base + 2] = i2; pi[base + 3] = i3; pi[base + 4] = i4;
    }
}

// merge the RSPLIT partial lists -> final stable top-5 indices per column
__global__ __launch_bounds__(256) void k_knnmerge(const float* __restrict__ pd,
        const int* __restrict__ pi, int* __restrict__ idxout) {
    int q = blockIdx.x * 256 + threadIdx.x;
    if (q >= BB * NPB) return;
    int b_ = q >> 12, j = q & (NPB - 1);
    float d0 = INFINITY, d1 = INFINITY, d2 = INFINITY, d3 = INFINITY, d4 = INFINITY;
    int i0 = 0x7FFFFFFF, i1 = 0x7FFFFFFF, i2 = 0x7FFFFFFF, i3 = 0x7FFFFFFF, i4 = 0x7FFFFFFF;
    for (int rs = 0; rs < RSPLIT; ++rs) {
        size_t base = ((size_t)(b_ * RSPLIT + rs) * NPB + j) * KK;
#pragma unroll
        for (int m = 0; m < KK; ++m)
            ins5lex(d0, d1, d2, d3, d4, i0, i1, i2, i3, i4, pd[base + m], pi[base + m]);
    }
    int* o = idxout + (size_t)q * KK;
    o[0] = i0; o[1] = i1; o[2] = i2; o[3] = i3; o[4] = i4;
}

// faithful scrambled-reshape edge value: g in [0, 2*ET)
__device__ __forceinline__ int edge_val(const int* __restrict__ idx, int g) {
    int r = g >> 2;          // / (2*BB)
    int rem = g & 3;
    int b_ = rem >> 1;
    if (rem & 1) return r / KK + b_ * NPB;               // centers (node-major)
    int j = r & (NPB - 1), k = r >> 12;                  // flat (k-major)
    return idx[(size_t)(b_ * NPB + j) * KK + k] + b_ * NPB;
}

// logprobs (direct-diff distance, scrambled gather) + edge arrays
__global__ __launch_bounds__(256) void k_lp_edges(const float* __restrict__ ge,
        const int* __restrict__ idx, const float* __restrict__ tptr,
        float* __restrict__ lp_out, int* __restrict__ e_src, int* __restrict__ e_dst) {
    int q = blockIdx.x * 256 + threadIdx.x;
    if (q >= ET) return;
    float t = clip_exp(tptr);
    int b_ = q / NKR;
    int r  = q - b_ * NKR;            // node-major: r = i*K + k
    int fl = idx[(size_t)(b_ * NPB + (r & (NPB - 1))) * KK + (r >> 12)];  // k-major gather
    int i  = r / KK;
    const float* ga = ge + (size_t)(b_ * NPB + fl) * DIM;
    const float* gb = ge + (size_t)(b_ * NPB + i) * DIM;
    float s = 0.f;
#pragma unroll 16
    for (int d = 0; d < DIM; ++d) { float df = ga[d] - gb[d]; s = fmaf(df, df, s); }
    lp_out[(size_t)q * 2] = -s * t;
    e_src[q] = edge_val(idx, q);
    e_dst[q] = edge_val(idx, q + ET);
}

__global__ __launch_bounds__(256) void k_init_acc(unsigned* __restrict__ acc) {
    acc[blockIdx.x * 256 + threadIdx.x] = 0x007FFFFFu;   // enc(-inf)
}

// EdgeConv: msg = cat[x_i, x_j - x_i] @ W[128,64] + b ; atomic segment-max over dst
__global__ __launch_bounds__(256) void k_edgeconv(const float* __restrict__ xf,
        const int* __restrict__ esrc, const int* __restrict__ edst,
        const float* __restrict__ W, const float* __restrict__ bias,
        unsigned* __restrict__ acc) {
    __shared__ float Wl[128][64];
    int tid = threadIdx.x;
    for (int v = tid; v < 128 * 64; v += 256) Wl[v >> 6][v & 63] = W[v];
    __syncthreads();
    int lane = tid & 63;
    int wid = blockIdx.x * 4 + (tid >> 6);
    float bc = bias[lane];
    int base = wid * 16;
    for (int m = 0; m < 16; ++m) {
        int e = base + m;
        int s = esrc[e], dvtx = edst[e];
        float xi = xf[(size_t)dvtx * 64 + lane];
        float xj = xf[(size_t)s * 64 + lane];
        float a = bc;
#pragma unroll
        for (int k = 0; k < 64; ++k) {
            float xik = __shfl(xi, k, 64);
            float xjk = __shfl(xj, k, 64);
            a = fmaf(xik, Wl[k][lane], a);
            a = fmaf(xjk - xik, Wl[64 + k][lane], a);
        }
        atomicMax(&acc[(size_t)dvtx * 64 + lane], enc_f(a));
    }
}

__global__ __launch_bounds__(256) void k_decode(const unsigned* __restrict__ acc,
        float* __restrict__ Y) {
    int v = blockIdx.x * 256 + threadIdx.x;
    Y[v] = fmaxf(dec_f(acc[v]), 0.0f);   // relu; empty segment (-inf) -> 0
}

// fc: out = leaky(x2 @ Wf1[64,32] + bf1, 0.1) @ Wf2[32,8] + bf2
__global__ __launch_bounds__(256) void k_final(const float* __restrict__ x2,
        const float* __restrict__ Wf1, const float* __restrict__ bf1,
        const float* __restrict__ Wf2, const float* __restrict__ bf2,
        float* __restrict__ out) {
    int i = blockIdx.x * 256 + threadIdx.x;
    const float* xr = x2 + (size_t)i * DIM;
    float xv[DIM];
#pragma unroll
    for (int d = 0; d < DIM; ++d) xv[d] = xr[d];
    float h[32];
#pragma unroll
    for (int c = 0; c < 32; ++c) {
        float a = bf1[c];
#pragma unroll
        for (int d = 0; d < DIM; ++d) a = fmaf(xv[d], Wf1[d * 32 + c], a);
        h[c] = a > 0.f ? a : 0.1f * a;
    }
#pragma unroll
    for (int o8 = 0; o8 < 8; ++o8) {
        float a = bf2[o8];
#pragma unroll
        for (int c = 0; c < 32; ++c) a = fmaf(h[c], Wf2[c * 8 + o8], a);
        out[(size_t)i * 8 + o8] = a;
    }
}

extern "C" void kernel_launch(void* const* d_in, const int* in_sizes, int n_in,
                              void* d_out, int out_size, void* d_ws, size_t ws_size,
                              hipStream_t stream) {
    const float* x    = (const float*)d_in[0];
    const float* Wpre = (const float*)d_in[1];
    const float* bpre = (const float*)d_in[2];
    const float* Wd1  = (const float*)d_in[3];
    const float* bd1  = (const float*)d_in[4];
    const float* t1   = (const float*)d_in[5];
    const float* Wc1  = (const float*)d_in[6];
    const float* bc1  = (const float*)d_in[7];
    const float* Wd2  = (const float*)d_in[8];
    const float* bd2  = (const float*)d_in[9];
    const float* t2   = (const float*)d_in[10];
    const float* Wc2  = (const float*)d_in[11];
    const float* bc2  = (const float*)d_in[12];
    const float* Wf1  = (const float*)d_in[13];
    const float* bf1  = (const float*)d_in[14];
    const float* Wf2  = (const float*)d_in[15];
    const float* bf2  = (const float*)d_in[16];

    float* ws = (float*)d_ws;
    float* x0   = ws;
    float* ge1  = x0  + (size_t)NN * DIM;
    float* x1v  = ge1 + (size_t)NN * DIM;
    float* ge2  = x1v + (size_t)NN * DIM;
    float* x2v  = ge2 + (size_t)NN * DIM;
    float* sqv  = x2v + (size_t)NN * DIM;
    float* pd   = sqv + NN;
    int*   pi   = (int*)(pd + (size_t)BB * RSPLIT * NPB * KK);
    int*   idx1 = pi + (size_t)BB * RSPLIT * NPB * KK;
    int*   idx2 = idx1 + ET;
    int*   es1  = idx2 + ET;
    int*   ed1  = es1 + ET;
    int*   es2  = ed1 + ET;
    int*   ed2  = es2 + ET;
    unsigned* accb = (unsigned*)(ed2 + ET);

    float* outp = (float*)d_out;
    float* lpp  = outp + (size_t)NN * 8;   // lprobs base (stride 2 over layers)

    dim3 blk(256);

    k_prefc<<<NN / 4, blk, 0, stream>>>(x, Wpre, bpre, x0);
    k_embed<<<NN / 4, blk, 0, stream>>>(x0, nullptr, Wd1, bd1, ge1, sqv);
    k_knn<<<dim3(NPB / 64, BB, RSPLIT), blk, 0, stream>>>(ge1, sqv, t1, pd, pi);
    k_knnmerge<<<(BB * NPB) / 256, blk, 0, stream>>>(pd, pi, idx1);
    k_lp_edges<<<ET / 256, blk, 0, stream>>>(ge1, idx1, t1, lpp + 0, es1, ed1);
    k_init_acc<<<(NN * DIM) / 256, blk, 0, stream>>>(accb);
    k_edgeconv<<<ET / 64, blk, 0, stream>>>(x0, es1, ed1, Wc1, bc1, accb);
    k_decode<<<(NN * DIM) / 256, blk, 0, stream>>>(accb, x1v);

    k_embed<<<NN / 4, blk, 0, stream>>>(ge1, x1v, Wd2, bd2, ge2, sqv);
    k_knn<<<dim3(NPB / 64, BB, RSPLIT), blk, 0, stream>>>(ge2, sqv, t2, pd, pi);
    k_knnmerge<<<(BB * NPB) / 256, blk, 0, stream>>>(pd, pi, idx2);
    k_lp_edges<<<ET / 256, blk, 0, stream>>>(ge2, idx2, t2, lpp + 1, es2, ed2);
    k_init_acc<<<(NN * DIM) / 256, blk, 0, stream>>>(accb);
    k_edgeconv<<<ET / 64, blk, 0, stream>>>(x1v, es2, ed2, Wc2, bc2, accb);
    k_decode<<<(NN * DIM) / 256, blk, 0, stream>>>(accb, x2v);

    k_final<<<NN / 256, blk, 0, stream>>>(x2v, Wf1, bf1, Wf2, bf2, outp);
}

// Round 4
// 553.561 us; speedup vs baseline: 1.1481x; 1.1481x over previous
//
#include <hip/hip_runtime.h>
#include <math.h>

#define NPB 4096
#define BB 2
#define NN (NPB*BB)          // 8192
#define DIM 64
#define KK 5
#define NKR (NPB*KK)         // 20480
#define ET (BB*NKR)          // 40960 edges (= b*n*K)
#define RSPLIT 8
#define TPS ((NPB/RSPLIT)/64)   // 8 tiles per split
#define LROW 68              // LDS row stride in floats (17 float4, 16B aligned)

__device__ __forceinline__ float clip_exp(const float* tptr) {
    return expf(fminf(fmaxf(tptr[0], -5.0f), 5.0f));
}

// order-preserving float <-> uint map for atomicMax-based segment max
__device__ __forceinline__ unsigned enc_f(float f) {
    unsigned u = __float_as_uint(f);
    return (u & 0x80000000u) ? ~u : (u | 0x80000000u);
}
__device__ __forceinline__ float dec_f(unsigned e) {
    unsigned u = (e & 0x80000000u) ? (e ^ 0x80000000u) : ~e;
    return __uint_as_float(u);
}

// insert (dd,ii) into ascending top-5; strict-less compare (valid when ii is
// scanned in increasing order: equal-d keeps the earlier/lower index)
__device__ __forceinline__ void ins5(float& d0, float& d1, float& d2, float& d3, float& d4,
                                     int& i0, int& i1, int& i2, int& i3, int& i4,
                                     float dd, int ii) {
    if (dd < d4) {
        bool c0 = dd < d0, c1 = dd < d1, c2 = dd < d2, c3 = dd < d3;
        d4 = c3 ? d3 : dd;             i4 = c3 ? i3 : ii;
        d3 = c2 ? d2 : (c3 ? dd : d3); i3 = c2 ? i2 : (c3 ? ii : i3);
        d2 = c1 ? d1 : (c2 ? dd : d2); i2 = c1 ? i1 : (c2 ? ii : i2);
        d1 = c0 ? d0 : (c1 ? dd : d1); i1 = c0 ? i0 : (c1 ? ii : i1);
        d0 = c0 ? dd : d0;             i0 = c0 ? ii : i0;
    }
}

// lexicographic (d, idx) insert — for merging lists in arbitrary order
__device__ __forceinline__ void ins5lex(float& d0, float& d1, float& d2, float& d3, float& d4,
                                        int& i0, int& i1, int& i2, int& i3, int& i4,
                                        float dd, int ii) {
    bool c4 = (dd < d4) || (dd == d4 && ii < i4);
    if (c4) {
        bool c0 = (dd < d0) || (dd == d0 && ii < i0);
        bool c1 = (dd < d1) || (dd == d1 && ii < i1);
        bool c2 = (dd < d2) || (dd == d2 && ii < i2);
        bool c3 = (dd < d3) || (dd == d3 && ii < i3);
        d4 = c3 ? d3 : dd;             i4 = c3 ? i3 : ii;
        d3 = c2 ? d2 : (c3 ? dd : d3); i3 = c2 ? i2 : (c3 ? ii : i3);
        d2 = c1 ? d1 : (c2 ? dd : d2); i2 = c1 ? i1 : (c2 ? ii : i2);
        d1 = c0 ? d0 : (c1 ? dd : d1); i1 = c0 ? i0 : (c1 ? ii : i1);
        d0 = c0 ? dd : d0;             i0 = c0 ? ii : i0;
    }
}

// ---------------- pre_fc: Y = leaky_relu(X[8192,32] @ W[32,64] + b, 0.1)
__global__ __launch_bounds__(256) void k_prefc(const float* __restrict__ X,
        const float* __restrict__ W, const float* __restrict__ bias,
        float* __restrict__ Y) {
    int row = blockIdx.x * 4 + (threadIdx.x >> 6);
    int c = threadIdx.x & 63;
    const float* xr = X + (size_t)row * 32;
    float acc = bias[c];
#pragma unroll
    for (int d = 0; d < 32; ++d) acc = fmaf(xr[d], W[d * 64 + c], acc);
    Y[(size_t)row * 64 + c] = acc > 0.f ? acc : 0.1f * acc;
}

// ---------------- embed: Y = X1@W[0:64] (+ X2@W[64:128]) + b ; also sq-norms of rows of Y
__global__ __launch_bounds__(256) void k_embed(const float* __restrict__ X1,
        const float* __restrict__ X2, const float* __restrict__ W,
        const float* __restrict__ bias, float* __restrict__ Y,
        float* __restrict__ sqout) {
    int row = blockIdx.x * 4 + (threadIdx.x >> 6);
    int c = threadIdx.x & 63;
    float acc = bias[c];
    const float* x1r = X1 + (size_t)row * DIM;
#pragma unroll 16
    for (int d = 0; d < DIM; ++d) acc = fmaf(x1r[d], W[d * DIM + c], acc);
    if (X2) {
        const float* x2r = X2 + (size_t)row * DIM;
#pragma unroll 16
        for (int d = 0; d < DIM; ++d) acc = fmaf(x2r[d], W[(DIM + d) * DIM + c], acc);
    }
    Y[(size_t)row * DIM + c] = acc;
    float s = acc * acc;
#pragma unroll
    for (int off = 32; off; off >>= 1) s += __shfl_xor(s, off, 64);
    if (c == 0) sqout[row] = s;
}

#define DOT4(A,B,ACC) { ACC = fmaf(A.x,B.x,ACC); ACC = fmaf(A.y,B.y,ACC); \
                        ACC = fmaf(A.z,B.z,ACC); ACC = fmaf(A.w,B.w,ACC); }

// ---------------- knn: per (col-block, batch, row-split) partial stable top-5 smallest
// B-tile (gej) cols owned c-strided (cg + 16c) -> ds_read_b128 2-way (free) banks.
__global__ __launch_bounds__(256, 4) void k_knn(const float* __restrict__ ge,
        const float* __restrict__ sq, const float* __restrict__ tptr,
        float* __restrict__ pd, int* __restrict__ pi) {
    __shared__ float smem[2 * 64 * LROW];       // 34816 B -> 4 blocks/CU
    float* gejS = smem;                          // B tile [64][68]
    float* geiS = smem + 64 * LROW;              // A tile [64][68]
    // merge overlay (re-used B-tile space, after barrier): [4 waves][64 cols][5]
    float* mbd = smem;                           // 1280 floats
    int*   mbi = (int*)(smem + 1280);            // 1280 ints

    const int b_ = blockIdx.y;
    const int rs = blockIdx.z;
    const int jblk = blockIdx.x * 64;
    const float* geb = ge + (size_t)b_ * NPB * DIM;
    const float* sqb = sq + (size_t)b_ * NPB;
    const float t = clip_exp(tptr);
    const int tid = threadIdx.x;

    // stage B tile (cols of the distance matrix)
    for (int v = tid; v < 64 * 16; v += 256) {
        int r = v >> 4, d4 = v & 15;
        *(float4*)&gejS[r * LROW + d4 * 4] =
            *(const float4*)&geb[(size_t)(jblk + r) * DIM + d4 * 4];
    }

    const int rg = tid >> 4, cg = tid & 15;
    float td[4][5]; int ti[4][5];
#pragma unroll
    for (int c = 0; c < 4; ++c)
#pragma unroll
        for (int m = 0; m < 5; ++m) { td[c][m] = INFINITY; ti[c][m] = 0x7FFFFFFF; }
    float sjv[4];
#pragma unroll
    for (int c = 0; c < 4; ++c) sjv[c] = sqb[jblk + cg + 16 * c];

    const float4* AF4 = (const float4*)geiS;
    const float4* BF4 = (const float4*)gejS;

    const int tb0 = rs * TPS;
    for (int tb = tb0; tb < tb0 + TPS; ++tb) {
        __syncthreads();
        for (int v = tid; v < 64 * 16; v += 256) {
            int r = v >> 4, d4 = v & 15;
            *(float4*)&geiS[r * LROW + d4 * 4] =
                *(const float4*)&geb[(size_t)(tb * 64 + r) * DIM + d4 * 4];
        }
        __syncthreads();
        float acc[4][4];
#pragma unroll
        for (int r = 0; r < 4; ++r)
#pragma unroll
            for (int c = 0; c < 4; ++c) acc[r][c] = 0.f;
#pragma unroll 4
        for (int d4 = 0; d4 < 16; ++d4) {
            float4 a0 = AF4[(rg * 4 + 0) * 17 + d4];
            float4 a1 = AF4[(rg * 4 + 1) * 17 + d4];
            float4 a2 = AF4[(rg * 4 + 2) * 17 + d4];
            float4 a3 = AF4[(rg * 4 + 3) * 17 + d4];
            float4 b0 = BF4[(cg +  0) * 17 + d4];
            float4 b1 = BF4[(cg + 16) * 17 + d4];
            float4 b2 = BF4[(cg + 32) * 17 + d4];
            float4 b3 = BF4[(cg + 48) * 17 + d4];
            DOT4(a0, b0, acc[0][0]) DOT4(a0, b1, acc[0][1])
            DOT4(a0, b2, acc[0][2]) DOT4(a0, b3, acc[0][3])
            DOT4(a1, b0, acc[1][0]) DOT4(a1, b1, acc[1][1])
            DOT4(a1, b2, acc[1][2]) DOT4(a1, b3, acc[1][3])
            DOT4(a2, b0, acc[2][0]) DOT4(a2, b1, acc[2][1])
            DOT4(a2, b2, acc[2][2]) DOT4(a2, b3, acc[2][3])
            DOT4(a3, b0, acc[3][0]) DOT4(a3, b1, acc[3][1])
            DOT4(a3, b2, acc[3][2]) DOT4(a3, b3, acc[3][3])
        }
#pragma unroll
        for (int r = 0; r < 4; ++r) {
            int i = tb * 64 + rg * 4 + r;
            float si = sqb[i];
#pragma unroll
            for (int c = 0; c < 4; ++c) {
                float md = fmaxf(si + sjv[c] - 2.0f * acc[r][c], 0.0f) * t;
                ins5(td[c][0], td[c][1], td[c][2], td[c][3], td[c][4],
                     ti[c][0], ti[c][1], ti[c][2], ti[c][3], ti[c][4], md, i);
            }
        }
    }

    // in-wave merge across rg groups (lanes l, l^16, l^32): lexicographic
#pragma unroll
    for (int step = 16; step <= 32; step <<= 1) {
#pragma unroll
        for (int c = 0; c < 4; ++c) {
            float od[5]; int oi[5];
#pragma unroll
            for (int m = 0; m < 5; ++m) {
                od[m] = __shfl_xor(td[c][m], step, 64);
                oi[m] = __shfl_xor(ti[c][m], step, 64);
            }
#pragma unroll
            for (int m = 0; m < 5; ++m)
                ins5lex(td[c][0], td[c][1], td[c][2], td[c][3], td[c][4],
                        ti[c][0], ti[c][1], ti[c][2], ti[c][3], ti[c][4], od[m], oi[m]);
        }
    }

    __syncthreads();   // all waves done reading tiles; safe to overlay merge buffer
    int lane = tid & 63, wv = tid >> 6;
    if (lane < 16) {
#pragma unroll
        for (int c = 0; c < 4; ++c) {
            int col = lane + 16 * c;
#pragma unroll
            for (int m = 0; m < 5; ++m) {
                mbd[(wv * 64 + col) * 5 + m] = td[c][m];
                mbi[(wv * 64 + col) * 5 + m] = ti[c][m];
            }
        }
    }
    __syncthreads();
    if (tid < 64) {
        float d0 = INFINITY, d1 = INFINITY, d2 = INFINITY, d3 = INFINITY, d4 = INFINITY;
        int i0 = 0x7FFFFFFF, i1 = 0x7FFFFFFF, i2 = 0x7FFFFFFF, i3 = 0x7FFFFFFF, i4 = 0x7FFFFFFF;
        for (int w = 0; w < 4; ++w)
#pragma unroll
            for (int m = 0; m < 5; ++m)
                ins5lex(d0, d1, d2, d3, d4, i0, i1, i2, i3, i4,
                        mbd[(w * 64 + tid) * 5 + m], mbi[(w * 64 + tid) * 5 + m]);
        size_t base = ((size_t)(b_ * RSPLIT + rs) * NPB + jblk + tid) * KK;
        pd[base + 0] = d0; pd[base + 1] = d1; pd[base + 2] = d2; pd[base + 3] = d3; pd[base + 4] = d4;
        pi[base + 0] = i0; pi[base + 1] = i1; pi[base + 2] = i2; pi[base + 3] = i3; pi[base + 4] = i4;
    }
}

// merge the RSPLIT partial lists -> final stable top-5 indices per column
__global__ __launch_bounds__(256) void k_knnmerge(const float* __restrict__ pd,
        const int* __restrict__ pi, int* __restrict__ idxout) {
    int q = blockIdx.x * 256 + threadIdx.x;
    if (q >= BB * NPB) return;
    int b_ = q >> 12, j = q & (NPB - 1);
    float d0 = INFINITY, d1 = INFINITY, d2 = INFINITY, d3 = INFINITY, d4 = INFINITY;
    int i0 = 0x7FFFFFFF, i1 = 0x7FFFFFFF, i2 = 0x7FFFFFFF, i3 = 0x7FFFFFFF, i4 = 0x7FFFFFFF;
    for (int rs = 0; rs < RSPLIT; ++rs) {
        size_t base = ((size_t)(b_ * RSPLIT + rs) * NPB + j) * KK;
#pragma unroll
        for (int m = 0; m < KK; ++m)
            ins5lex(d0, d1, d2, d3, d4, i0, i1, i2, i3, i4, pd[base + m], pi[base + m]);
    }
    int* o = idxout + (size_t)q * KK;
    o[0] = i0; o[1] = i1; o[2] = i2; o[3] = i3; o[4] = i4;
}

// faithful scrambled-reshape edge value: g in [0, 2*ET)
__device__ __forceinline__ int edge_val(const int* __restrict__ idx, int g) {
    int r = g >> 2;          // / (2*BB)
    int rem = g & 3;
    int b_ = rem >> 1;
    if (rem & 1) return r / KK + b_ * NPB;               // centers (node-major)
    int j = r & (NPB - 1), k = r >> 12;                  // flat (k-major)
    return idx[(size_t)(b_ * NPB + j) * KK + k] + b_ * NPB;
}

// logprobs (direct-diff distance, scrambled gather) + edge arrays
__global__ __launch_bounds__(256) void k_lp_edges(const float* __restrict__ ge,
        const int* __restrict__ idx, const float* __restrict__ tptr,
        float* __restrict__ lp_out, int* __restrict__ e_src, int* __restrict__ e_dst) {
    int q = blockIdx.x * 256 + threadIdx.x;
    if (q >= ET) return;
    float t = clip_exp(tptr);
    int b_ = q / NKR;
    int r  = q - b_ * NKR;            // node-major: r = i*K + k
    int fl = idx[(size_t)(b_ * NPB + (r & (NPB - 1))) * KK + (r >> 12)];  // k-major gather
    int i  = r / KK;
    const float* ga = ge + (size_t)(b_ * NPB + fl) * DIM;
    const float* gb = ge + (size_t)(b_ * NPB + i) * DIM;
    float s = 0.f;
#pragma unroll 16
    for (int d = 0; d < DIM; ++d) { float df = ga[d] - gb[d]; s = fmaf(df, df, s); }
    lp_out[(size_t)q * 2] = -s * t;
    e_src[q] = edge_val(idx, q);
    e_dst[q] = edge_val(idx, q + ET);
}

__global__ __launch_bounds__(256) void k_init_acc(unsigned* __restrict__ acc) {
    acc[blockIdx.x * 256 + threadIdx.x] = 0x007FFFFFu;   // enc(-inf)
}

// EdgeConv: msg = cat[x_i, x_j - x_i] @ W[128,64] + b ; atomic segment-max over dst
__global__ __launch_bounds__(256) void k_edgeconv(const float* __restrict__ xf,
        const int* __restrict__ esrc, const int* __restrict__ edst,
        const float* __restrict__ W, const float* __restrict__ bias,
        unsigned* __restrict__ acc) {
    __shared__ float Wl[128][64];
    int tid = threadIdx.x;
    for (int v = tid; v < 128 * 64; v += 256) Wl[v >> 6][v & 63] = W[v];
    __syncthreads();
    int lane = tid & 63;
    int wid = blockIdx.x * 4 + (tid >> 6);
    float bc = bias[lane];
    int base = wid * 16;
    for (int m = 0; m < 16; ++m) {
        int e = base + m;
        int s = esrc[e], dvtx = edst[e];
        float xi = xf[(size_t)dvtx * 64 + lane];
        float xj = xf[(size_t)s * 64 + lane];
        float a = bc;
#pragma unroll
        for (int k = 0; k < 64; ++k) {
            float xik = __shfl(xi, k, 64);
            float xjk = __shfl(xj, k, 64);
            a = fmaf(xik, Wl[k][lane], a);
            a = fmaf(xjk - xik, Wl[64 + k][lane], a);
        }
        atomicMax(&acc[(size_t)dvtx * 64 + lane], enc_f(a));
    }
}

__global__ __launch_bounds__(256) void k_decode(const unsigned* __restrict__ acc,
        float* __restrict__ Y) {
    int v = blockIdx.x * 256 + threadIdx.x;
    Y[v] = fmaxf(dec_f(acc[v]), 0.0f);   // relu; empty segment (-inf) -> 0
}

// fc: out = leaky(x2 @ Wf1[64,32] + bf1, 0.1) @ Wf2[32,8] + bf2
__global__ __launch_bounds__(256) void k_final(const float* __restrict__ x2,
        const float* __restrict__ Wf1, const float* __restrict__ bf1,
        const float* __restrict__ Wf2, const float* __restrict__ bf2,
        float* __restrict__ out) {
    int i = blockIdx.x * 256 + threadIdx.x;
    const float* xr = x2 + (size_t)i * DIM;
    float xv[DIM];
#pragma unroll
    for (int d = 0; d < DIM; ++d) xv[d] = xr[d];
    float h[32];
#pragma unroll
    for (int c = 0; c < 32; ++c) {
        float a = bf1[c];
#pragma unroll
        for (int d = 0; d < DIM; ++d) a = fmaf(xv[d], Wf1[d * 32 + c], a);
        h[c] = a > 0.f ? a : 0.1f * a;
    }
#pragma unroll
    for (int o8 = 0; o8 < 8; ++o8) {
        float a = bf2[o8];
#pragma unroll
        for (int c = 0; c < 32; ++c) a = fmaf(h[c], Wf2[c * 8 + o8], a);
        out[(size_t)i * 8 + o8] = a;
    }
}

extern "C" void kernel_launch(void* const* d_in, const int* in_sizes, int n_in,
                              void* d_out, int out_size, void* d_ws, size_t ws_size,
                              hipStream_t stream) {
    const float* x    = (const float*)d_in[0];
    const float* Wpre = (const float*)d_in[1];
    const float* bpre = (const float*)d_in[2];
    const float* Wd1  = (const float*)d_in[3];
    const float* bd1  = (const float*)d_in[4];
    const float* t1   = (const float*)d_in[5];
    const float* Wc1  = (const float*)d_in[6];
    const float* bc1  = (const float*)d_in[7];
    const float* Wd2  = (const float*)d_in[8];
    const float* bd2  = (const float*)d_in[9];
    const float* t2   = (const float*)d_in[10];
    const float* Wc2  = (const float*)d_in[11];
    const float* bc2  = (const float*)d_in[12];
    const float* Wf1  = (const float*)d_in[13];
    const float* bf1  = (const float*)d_in[14];
    const float* Wf2  = (const float*)d_in[15];
    const float* bf2  = (const float*)d_in[16];

    float* ws = (float*)d_ws;
    float* x0   = ws;
    float* ge1  = x0  + (size_t)NN * DIM;
    float* x1v  = ge1 + (size_t)NN * DIM;
    float* ge2  = x1v + (size_t)NN * DIM;
    float* x2v  = ge2 + (size_t)NN * DIM;
    float* sqv  = x2v + (size_t)NN * DIM;
    float* pd   = sqv + NN;
    int*   pi   = (int*)(pd + (size_t)BB * RSPLIT * NPB * KK);
    int*   idx1 = pi + (size_t)BB * RSPLIT * NPB * KK;
    int*   idx2 = idx1 + ET;
    int*   es1  = idx2 + ET;
    int*   ed1  = es1 + ET;
    int*   es2  = ed1 + ET;
    int*   ed2  = es2 + ET;
    unsigned* accb = (unsigned*)(ed2 + ET);

    float* outp = (float*)d_out;
    float* lpp  = outp + (size_t)NN * 8;   // lprobs base (stride 2 over layers)

    dim3 blk(256);

    k_prefc<<<NN / 4, blk, 0, stream>>>(x, Wpre, bpre, x0);
    k_embed<<<NN / 4, blk, 0, stream>>>(x0, nullptr, Wd1, bd1, ge1, sqv);
    k_knn<<<dim3(NPB / 64, BB, RSPLIT), blk, 0, stream>>>(ge1, sqv, t1, pd, pi);
    k_knnmerge<<<(BB * NPB) / 256, blk, 0, stream>>>(pd, pi, idx1);
    k_lp_edges<<<ET / 256, blk, 0, stream>>>(ge1, idx1, t1, lpp + 0, es1, ed1);
    k_init_acc<<<(NN * DIM) / 256, blk, 0, stream>>>(accb);
    k_edgeconv<<<ET / 64, blk, 0, stream>>>(x0, es1, ed1, Wc1, bc1, accb);
    k_decode<<<(NN * DIM) / 256, blk, 0, stream>>>(accb, x1v);

    k_embed<<<NN / 4, blk, 0, stream>>>(ge1, x1v, Wd2, bd2, ge2, sqv);
    k_knn<<<dim3(NPB / 64, BB, RSPLIT), blk, 0, stream>>>(ge2, sqv, t2, pd, pi);
    k_knnmerge<<<(BB * NPB) / 256, blk, 0, stream>>>(pd, pi, idx2);
    k_lp_edges<<<ET / 256, blk, 0, stream>>>(ge2, idx2, t2, lpp + 1, es2, ed2);
    k_init_acc<<<(NN * DIM) / 256, blk, 0, stream>>>(accb);
    k_edgeconv<<<ET / 64, blk, 0, stream>>>(x1v, es2, ed2, Wc2, bc2, accb);
    k_decode<<<(NN * DIM) / 256, blk, 0, stream>>>(accb, x2v);

    k_final<<<NN / 256, blk, 0, stream>>>(x2v, Wf1, bf1, Wf2, bf2, outp);
}

// Round 6
// 462.524 us; speedup vs baseline: 1.3741x; 1.1968x over previous
//
#include <hip/hip_runtime.h>
#include <math.h>

#define NPB 4096
#define BB 2
#define NN (NPB*BB)          // 8192
#define DIM 64
#define KK 5
#define NKR (NPB*KK)         // 20480
#define ET (BB*NKR)          // 40960 edges
#define RSPLIT 8
#define CTILE 128            // cols per block
#define RTILE 128            // rows per A tile
#define TPS 4                // row-tiles per block: 8*4*128 = 4096
#define LROW 68              // LDS row stride floats (17 float4)

__device__ __forceinline__ float clip_exp(const float* tptr) {
    return expf(fminf(fmaxf(tptr[0], -5.0f), 5.0f));
}

__device__ __forceinline__ unsigned enc_f(float f) {
    unsigned u = __float_as_uint(f);
    return (u & 0x80000000u) ? ~u : (u | 0x80000000u);
}
__device__ __forceinline__ float dec_f(unsigned e) {
    unsigned u = (e & 0x80000000u) ? (e ^ 0x80000000u) : ~e;
    return __uint_as_float(u);
}

// ascending top-5 insert; strict-less (stable when scanned in ascending index)
__device__ __forceinline__ void ins5(float& d0, float& d1, float& d2, float& d3, float& d4,
                                     int& i0, int& i1, int& i2, int& i3, int& i4,
                                     float dd, int ii) {
    if (dd < d4) {
        bool c0 = dd < d0, c1 = dd < d1, c2 = dd < d2, c3 = dd < d3;
        d4 = c3 ? d3 : dd;             i4 = c3 ? i3 : ii;
        d3 = c2 ? d2 : (c3 ? dd : d3); i3 = c2 ? i2 : (c3 ? ii : i3);
        d2 = c1 ? d1 : (c2 ? dd : d2); i2 = c1 ? i1 : (c2 ? ii : i2);
        d1 = c0 ? d0 : (c1 ? dd : d1); i1 = c0 ? i0 : (c1 ? ii : i1);
        d0 = c0 ? dd : d0;             i0 = c0 ? ii : i0;
    }
}

// lexicographic (d, idx) insert — merge partial lists in arbitrary order
__device__ __forceinline__ void ins5lex(float& d0, float& d1, float& d2, float& d3, float& d4,
                                        int& i0, int& i1, int& i2, int& i3, int& i4,
                                        float dd, int ii) {
    bool c4 = (dd < d4) || (dd == d4 && ii < i4);
    if (c4) {
        bool c0 = (dd < d0) || (dd == d0 && ii < i0);
        bool c1 = (dd < d1) || (dd == d1 && ii < i1);
        bool c2 = (dd < d2) || (dd == d2 && ii < i2);
        bool c3 = (dd < d3) || (dd == d3 && ii < i3);
        d4 = c3 ? d3 : dd;             i4 = c3 ? i3 : ii;
        d3 = c2 ? d2 : (c3 ? dd : d3); i3 = c2 ? i2 : (c3 ? ii : i3);
        d2 = c1 ? d1 : (c2 ? dd : d2); i2 = c1 ? i1 : (c2 ? ii : i2);
        d1 = c0 ? d0 : (c1 ? dd : d1); i1 = c0 ? i0 : (c1 ? ii : i1);
        d0 = c0 ? dd : d0;             i0 = c0 ? ii : i0;
    }
}

// ---------------- pre_fc
__global__ __launch_bounds__(256) void k_prefc(const float* __restrict__ X,
        const float* __restrict__ W, const float* __restrict__ bias,
        float* __restrict__ Y) {
    int row = blockIdx.x * 4 + (threadIdx.x >> 6);
    int c = threadIdx.x & 63;
    const float* xr = X + (size_t)row * 32;
    float acc = bias[c];
#pragma unroll
    for (int d = 0; d < 32; ++d) acc = fmaf(xr[d], W[d * 64 + c], acc);
    Y[(size_t)row * 64 + c] = acc > 0.f ? acc : 0.1f * acc;
}

// ---------------- embed: Y = X1@W[0:64] (+ X2@W[64:128]) + b ; plus row sq-norms
__global__ __launch_bounds__(256) void k_embed(const float* __restrict__ X1,
        const float* __restrict__ X2, const float* __restrict__ W,
        const float* __restrict__ bias, float* __restrict__ Y,
        float* __restrict__ sqout) {
    int row = blockIdx.x * 4 + (threadIdx.x >> 6);
    int c = threadIdx.x & 63;
    float acc = bias[c];
    const float* x1r = X1 + (size_t)row * DIM;
#pragma unroll 16
    for (int d = 0; d < DIM; ++d) acc = fmaf(x1r[d], W[d * DIM + c], acc);
    if (X2) {
        const float* x2r = X2 + (size_t)row * DIM;
#pragma unroll 16
        for (int d = 0; d < DIM; ++d) acc = fmaf(x2r[d], W[(DIM + d) * DIM + c], acc);
    }
    Y[(size_t)row * DIM + c] = acc;
    float s = acc * acc;
#pragma unroll
    for (int off = 32; off; off >>= 1) s += __shfl_xor(s, off, 64);
    if (c == 0) sqout[row] = s;
}

// ---------------- P/Q for linearized EdgeConv:
// P = xf @ (W[0:64]-W[64:128]) + bias ; Q = xf @ W[64:128]
__global__ __launch_bounds__(256) void k_pq(const float* __restrict__ xf,
        const float* __restrict__ W, const float* __restrict__ bias,
        float* __restrict__ P, float* __restrict__ Q) {
    int row = blockIdx.x * 4 + (threadIdx.x >> 6);
    int c = threadIdx.x & 63;
    const float* xr = xf + (size_t)row * DIM;
    float ap = bias[c], aq = 0.f;
#pragma unroll 16
    for (int d = 0; d < DIM; ++d) {
        float xv = xr[d];
        float w1 = W[(DIM + d) * DIM + c];
        aq = fmaf(xv, w1, aq);
        ap = fmaf(xv, W[d * DIM + c] - w1, ap);
    }
    P[(size_t)row * DIM + c] = ap;
    Q[(size_t)row * DIM + c] = aq;
}

#define DOT4(A,B,ACC) { ACC = fmaf(A.x,B.x,ACC); ACC = fmaf(A.y,B.y,ACC); \
                        ACC = fmaf(A.z,B.z,ACC); ACC = fmaf(A.w,B.w,ACC); }

// ---------------- knn: 128x128 tiles, 8x8 register micro-tile
__global__ __launch_bounds__(256, 2) void k_knn(const float* __restrict__ ge,
        const float* __restrict__ sq, const float* __restrict__ tptr,
        float* __restrict__ pd, int* __restrict__ pi) {
    __shared__ float smem[2 * RTILE * LROW];    // 69632 B -> 2 blocks/CU
    float* gejS = smem;                          // B tile [128][68]
    float* geiS = smem + RTILE * LROW;           // A tile [128][68]
    // merge overlay after barrier: [4 waves][128 cols][5]
    float* mbd = smem;                           // 2560 floats
    int*   mbi = (int*)(smem + 2560);            // 2560 ints

    const int b_ = blockIdx.y;
    const int rs = blockIdx.z;
    const int jblk = blockIdx.x * CTILE;
    const float* geb = ge + (size_t)b_ * NPB * DIM;
    const float* sqb = sq + (size_t)b_ * NPB;
    const float t = clip_exp(tptr);
    const int tid = threadIdx.x;

    // stage B tile (cols of the distance matrix): 128 rows x 16 float4
    for (int v = tid; v < RTILE * 16; v += 256) {
        int r = v >> 4, d4 = v & 15;
        *(float4*)&gejS[r * LROW + d4 * 4] =
            *(const float4*)&geb[(size_t)(jblk + r) * DIM + d4 * 4];
    }

    const int rg = tid >> 4, cg = tid & 15;      // rg 0..15 (8 rows each), cg 0..15 (8 cols)
    float td[8][5]; int ti[8][5];
#pragma unroll
    for (int c = 0; c < 8; ++c)
#pragma unroll
        for (int m = 0; m < 5; ++m) { td[c][m] = INFINITY; ti[c][m] = 0x7FFFFFFF; }
    float sjv[8];
#pragma unroll
    for (int c = 0; c < 8; ++c) sjv[c] = sqb[jblk + cg + 16 * c];

    const float4* AF4 = (const float4*)geiS;
    const float4* BF4 = (const float4*)gejS;

    const int tb0 = rs * TPS;
    for (int tb = tb0; tb < tb0 + TPS; ++tb) {
        __syncthreads();
        for (int v = tid; v < RTILE * 16; v += 256) {
            int r = v >> 4, d4 = v & 15;
            *(float4*)&geiS[r * LROW + d4 * 4] =
                *(const float4*)&geb[(size_t)(tb * RTILE + r) * DIM + d4 * 4];
        }
        __syncthreads();
        float acc[8][8];
#pragma unroll
        for (int r = 0; r < 8; ++r)
#pragma unroll
            for (int c = 0; c < 8; ++c) acc[r][c] = 0.f;
#pragma unroll 2
        for (int d4 = 0; d4 < 16; ++d4) {
            float4 av[8], bv[8];
#pragma unroll
            for (int r = 0; r < 8; ++r) av[r] = AF4[(rg * 8 + r) * 17 + d4];
#pragma unroll
            for (int c = 0; c < 8; ++c) bv[c] = BF4[(cg + 16 * c) * 17 + d4];
#pragma unroll
            for (int r = 0; r < 8; ++r)
#pragma unroll
                for (int c = 0; c < 8; ++c) DOT4(av[r], bv[c], acc[r][c])
        }
#pragma unroll
        for (int r = 0; r < 8; ++r) {
            int i = tb * RTILE + rg * 8 + r;
            float si = sqb[i];
#pragma unroll
            for (int c = 0; c < 8; ++c) {
                float md = fmaxf(si + sjv[c] - 2.0f * acc[r][c], 0.0f) * t;
                ins5(td[c][0], td[c][1], td[c][2], td[c][3], td[c][4],
                     ti[c][0], ti[c][1], ti[c][2], ti[c][3], ti[c][4], md, i);
            }
        }
    }

    // in-wave merge: lanes l, l^16, l^32 hold same cols (rg groups within wave)
#pragma unroll
    for (int step = 16; step <= 32; step <<= 1) {
#pragma unroll
        for (int c = 0; c < 8; ++c) {
            float od[5]; int oi[5];
#pragma unroll
            for (int m = 0; m < 5; ++m) {
                od[m] = __shfl_xor(td[c][m], step, 64);
                oi[m] = __shfl_xor(ti[c][m], step, 64);
            }
#pragma unroll
            for (int m = 0; m < 5; ++m)
                ins5lex(td[c][0], td[c][1], td[c][2], td[c][3], td[c][4],
                        ti[c][0], ti[c][1], ti[c][2], ti[c][3], ti[c][4], od[m], oi[m]);
        }
    }

    __syncthreads();   // tiles no longer needed; overlay merge buffer
    int lane = tid & 63, wv = tid >> 6;
    if (lane < 16) {
#pragma unroll
        for (int c = 0; c < 8; ++c) {
            int col = lane + 16 * c;
#pragma unroll
            for (int m = 0; m < 5; ++m) {
                mbd[(wv * CTILE + col) * 5 + m] = td[c][m];
                mbi[(wv * CTILE + col) * 5 + m] = ti[c][m];
            }
        }
    }
    __syncthreads();
    if (tid < CTILE) {
        float d0 = INFINITY, d1 = INFINITY, d2 = INFINITY, d3 = INFINITY, d4 = INFINITY;
        int i0 = 0x7FFFFFFF, i1 = 0x7FFFFFFF, i2 = 0x7FFFFFFF, i3 = 0x7FFFFFFF, i4 = 0x7FFFFFFF;
        for (int w = 0; w < 4; ++w)
#pragma unroll
            for (int m = 0; m < 5; ++m)
                ins5lex(d0, d1, d2, d3, d4, i0, i1, i2, i3, i4,
                        mbd[(w * CTILE + tid) * 5 + m], mbi[(w * CTILE + tid) * 5 + m]);
        size_t base = ((size_t)(b_ * RSPLIT + rs) * NPB + jblk + tid) * KK;
        pd[base + 0] = d0; pd[base + 1] = d1; pd[base + 2] = d2; pd[base + 3] = d3; pd[base + 4] = d4;
        pi[base + 0] = i0; pi[base + 1] = i1; pi[base + 2] = i2; pi[base + 3] = i3; pi[base + 4] = i4;
    }
}

// merge RSPLIT partial lists -> final stable top-5 indices per column
__global__ __launch_bounds__(256) void k_knnmerge(const float* __restrict__ pd,
        const int* __restrict__ pi, int* __restrict__ idxout) {
    int q = blockIdx.x * 256 + threadIdx.x;
    if (q >= BB * NPB) return;
    int b_ = q >> 12, j = q & (NPB - 1);
    float d0 = INFINITY, d1 = INFINITY, d2 = INFINITY, d3 = INFINITY, d4 = INFINITY;
    int i0 = 0x7FFFFFFF, i1 = 0x7FFFFFFF, i2 = 0x7FFFFFFF, i3 = 0x7FFFFFFF, i4 = 0x7FFFFFFF;
    for (int rs = 0; rs < RSPLIT; ++rs) {
        size_t base = ((size_t)(b_ * RSPLIT + rs) * NPB + j) * KK;
#pragma unroll
        for (int m = 0; m < KK; ++m)
            ins5lex(d0, d1, d2, d3, d4, i0, i1, i2, i3, i4, pd[base + m], pi[base + m]);
    }
    int* o = idxout + (size_t)q * KK;
    o[0] = i0; o[1] = i1; o[2] = i2; o[3] = i3; o[4] = i4;
}

// faithful scrambled-reshape edge value: g in [0, 2*ET)
__device__ __forceinline__ int edge_val(const int* __restrict__ idx, int g) {
    int r = g >> 2;
    int rem = g & 3;
    int b_ = rem >> 1;
    if (rem & 1) return r / KK + b_ * NPB;               // centers (node-major)
    int j = r & (NPB - 1), k = r >> 12;                  // flat (k-major)
    return idx[(size_t)(b_ * NPB + j) * KK + k] + b_ * NPB;
}

// logprobs + edge arrays
__global__ __launch_bounds__(256) void k_lp_edges(const float* __restrict__ ge,
        const int* __restrict__ idx, const float* __restrict__ tptr,
        float* __restrict__ lp_out, int* __restrict__ e_src, int* __restrict__ e_dst) {
    int q = blockIdx.x * 256 + threadIdx.x;
    if (q >= ET) return;
    float t = clip_exp(tptr);
    int b_ = q / NKR;
    int r  = q - b_ * NKR;
    int fl = idx[(size_t)(b_ * NPB + (r & (NPB - 1))) * KK + (r >> 12)];
    int i  = r / KK;
    const float* ga = ge + (size_t)(b_ * NPB + fl) * DIM;
    const float* gb = ge + (size_t)(b_ * NPB + i) * DIM;
    float s = 0.f;
#pragma unroll 16
    for (int d = 0; d < DIM; ++d) { float df = ga[d] - gb[d]; s = fmaf(df, df, s); }
    lp_out[(size_t)q * 2] = -s * t;
    e_src[q] = edge_val(idx, q);
    e_dst[q] = edge_val(idx, q + ET);
}

__global__ __launch_bounds__(256) void k_init_acc(unsigned* __restrict__ acc) {
    acc[blockIdx.x * 256 + threadIdx.x] = 0x007FFFFFu;   // enc(-inf)
}

// scatter: acc[dst][ch] = max(acc, Q[src][ch])  (1 thread per edge-channel)
__global__ __launch_bounds__(256) void k_scatter(const float* __restrict__ Q,
        const int* __restrict__ esrc, const int* __restrict__ edst,
        unsigned* __restrict__ acc) {
    int idx = blockIdx.x * 256 + threadIdx.x;
    int e = idx >> 6, ch = idx & 63;
    int s = esrc[e], d = edst[e];
    atomicMax(&acc[(size_t)d * DIM + ch], enc_f(Q[(size_t)s * DIM + ch]));
}

// decode: out = relu(max + P) with empty-segment -> 0  (P includes bias)
__global__ __launch_bounds__(256) void k_decode(const unsigned* __restrict__ acc,
        const float* __restrict__ P, float* __restrict__ Y) {
    int v = blockIdx.x * 256 + threadIdx.x;
    float m = dec_f(acc[v]);
    Y[v] = (m == -INFINITY) ? 0.0f : fmaxf(m + P[v], 0.0f);
}

// fc
__global__ __launch_bounds__(256) void k_final(const float* __restrict__ x2,
        const float* __restrict__ Wf1, const float* __restrict__ bf1,
        const float* __restrict__ Wf2, const float* __restrict__ bf2,
        float* __restrict__ out) {
    int i = blockIdx.x * 256 + threadIdx.x;
    const float* xr = x2 + (size_t)i * DIM;
    float xv[DIM];
#pragma unroll
    for (int d = 0; d < DIM; ++d) xv[d] = xr[d];
    float h[32];
#pragma unroll
    for (int c = 0; c < 32; ++c) {
        float a = bf1[c];
#pragma unroll
        for (int d = 0; d < DIM; ++d) a = fmaf(xv[d], Wf1[d * 32 + c], a);
        h[c] = a > 0.f ? a : 0.1f * a;
    }
#pragma unroll
    for (int o8 = 0; o8 < 8; ++o8) {
        float a = bf2[o8];
#pragma unroll
        for (int c = 0; c < 32; ++c) a = fmaf(h[c], Wf2[c * 8 + o8], a);
        out[(size_t)i * 8 + o8] = a;
    }
}

extern "C" void kernel_launch(void* const* d_in, const int* in_sizes, int n_in,
                              void* d_out, int out_size, void* d_ws, size_t ws_size,
                              hipStream_t stream) {
    const float* x    = (const float*)d_in[0];
    const float* Wpre = (const float*)d_in[1];
    const float* bpre = (const float*)d_in[2];
    const float* Wd1  = (const float*)d_in[3];
    const float* bd1  = (const float*)d_in[4];
    const float* t1   = (const float*)d_in[5];
    const float* Wc1  = (const float*)d_in[6];
    const float* bc1  = (const float*)d_in[7];
    const float* Wd2  = (const float*)d_in[8];
    const float* bd2  = (const float*)d_in[9];
    const float* t2   = (const float*)d_in[10];
    const float* Wc2  = (const float*)d_in[11];
    const float* bc2  = (const float*)d_in[12];
    const float* Wf1  = (const float*)d_in[13];
    const float* bf1  = (const float*)d_in[14];
    const float* Wf2  = (const float*)d_in[15];
    const float* bf2  = (const float*)d_in[16];

    float* ws = (float*)d_ws;
    float* x0   = ws;
    float* ge1  = x0  + (size_t)NN * DIM;
    float* x1v  = ge1 + (size_t)NN * DIM;
    float* ge2  = x1v + (size_t)NN * DIM;
    float* x2v  = ge2 + (size_t)NN * DIM;
    float* Pb   = x2v + (size_t)NN * DIM;
    float* Qb   = Pb  + (size_t)NN * DIM;
    float* sqv  = Qb  + (size_t)NN * DIM;
    float* pd   = sqv + NN;
    int*   pi   = (int*)(pd + (size_t)BB * RSPLIT * NPB * KK);
    int*   idx1 = pi + (size_t)BB * RSPLIT * NPB * KK;
    int*   idx2 = idx1 + ET;
    int*   es1  = idx2 + ET;
    int*   ed1  = es1 + ET;
    int*   es2  = ed1 + ET;
    int*   ed2  = es2 + ET;
    unsigned* accb = (unsigned*)(ed2 + ET);

    float* outp = (float*)d_out;
    float* lpp  = outp + (size_t)NN * 8;

    dim3 blk(256);

    k_prefc<<<NN / 4, blk, 0, stream>>>(x, Wpre, bpre, x0);
    k_embed<<<NN / 4, blk, 0, stream>>>(x0, nullptr, Wd1, bd1, ge1, sqv);
    k_knn<<<dim3(NPB / CTILE, BB, RSPLIT), blk, 0, stream>>>(ge1, sqv, t1, pd, pi);
    k_knnmerge<<<(BB * NPB) / 256, blk, 0, stream>>>(pd, pi, idx1);
    k_lp_edges<<<ET / 256, blk, 0, stream>>>(ge1, idx1, t1, lpp + 0, es1, ed1);
    k_pq<<<NN / 4, blk, 0, stream>>>(x0, Wc1, bc1, Pb, Qb);
    k_init_acc<<<(NN * DIM) / 256, blk, 0, stream>>>(accb);
    k_scatter<<<(ET * 64) / 256, blk, 0, stream>>>(Qb, es1, ed1, accb);
    k_decode<<<(NN * DIM) / 256, blk, 0, stream>>>(accb, Pb, x1v);

    k_embed<<<NN / 4, blk, 0, stream>>>(ge1, x1v, Wd2, bd2, ge2, sqv);
    k_knn<<<dim3(NPB / CTILE, BB, RSPLIT), blk, 0, stream>>>(ge2, sqv, t2, pd, pi);
    k_knnmerge<<<(BB * NPB) / 256, blk, 0, stream>>>(pd, pi, idx2);
    k_lp_edges<<<ET / 256, blk, 0, stream>>>(ge2, idx2, t2, lpp + 1, es2, ed2);
    k_pq<<<NN / 4, blk, 0, stream>>>(x1v, Wc2, bc2, Pb, Qb);
    k_init_acc<<<(NN * DIM) / 256, blk, 0, stream>>>(accb);
    k_scatter<<<(ET * 64) / 256, blk, 0, stream>>>(Qb, es2, ed2, accb);
    k_decode<<<(NN * DIM) / 256, blk, 0, stream>>>(accb, Pb, x2v);

    k_final<<<NN / 256, blk, 0, stream>>>(x2v, Wf1, bf1, Wf2, bf2, outp);
}